// Round 2
// baseline (126.256 us; speedup 1.0000x reference)
//
#include <hip/hip_runtime.h>

// out[b,c,h,w] = x[b,c,h,w] + pe(c,h)
//   pe(c,h) = sin(h * 10000^(-(c&~1)/C)) if c even, cos(...) if c odd
// x: (16, 64, 256, 256) fp32 NCHW. pe depends only on (c,h) -> compute once,
// reuse across all 16 batches (batch stride = C*H*W = 4 MB).

typedef float f32x4 __attribute__((ext_vector_type(4)));

constexpr int B_ = 16, C_ = 64, H_ = 256, W_ = 256;
constexpr int BATCH4 = C_ * H_ * W_ / 4;  // float4s per batch slice = 1,048,576

__global__ void __launch_bounds__(256) PositionalEncoding_56805237457391_kernel(
    const f32x4* __restrict__ x, f32x4* __restrict__ out) {
    const float LOG2_10000_OVER_C = 13.287712379549449f / 64.0f;  // log2(1e4)/C

    const int stride = gridDim.x * blockDim.x;
    for (int i = blockIdx.x * blockDim.x + threadIdx.x; i < BATCH4; i += stride) {
        // Within one batch slice: row = c*H + h, 64 float4s per row (W/4).
        const int row = i >> 6;
        const int h   = row & (H_ - 1);
        const int c   = row >> 8;  // 0..63

        const float freq = exp2f(-(float)(c & ~1) * LOG2_10000_OVER_C);
        const float arg  = (float)h * freq;
        const float pe   = (c & 1) ? cosf(arg) : sinf(arg);

        const f32x4* xp = x + i;
        f32x4*       op = out + i;

        f32x4 v[B_];
#pragma unroll
        for (int b = 0; b < B_; ++b)
            v[b] = __builtin_nontemporal_load(xp + (size_t)b * BATCH4);
#pragma unroll
        for (int b = 0; b < B_; ++b)
            __builtin_nontemporal_store(v[b] + pe, op + (size_t)b * BATCH4);
    }
}

extern "C" void kernel_launch(void* const* d_in, const int* in_sizes, int n_in,
                              void* d_out, int out_size, void* d_ws, size_t ws_size,
                              hipStream_t stream) {
    const f32x4* x = (const f32x4*)d_in[0];
    f32x4* out = (f32x4*)d_out;

    const int block = 256;
    int grid = (BATCH4 + block - 1) / block;  // 4096
    if (grid > 2048) grid = 2048;             // grid-stride: 2 iters/thread

    PositionalEncoding_56805237457391_kernel<<<grid, block, 0, stream>>>(x, out);
}

// Round 3
// 116.971 us; speedup vs baseline: 1.0794x; 1.0794x over previous
//
#include <hip/hip_runtime.h>

// out[b,c,h,w] = x[b,c,h,w] + pe(c,h)
// Two kernels:
//   1. pe_table: 64x256 fp32 table pe[c*H+h] into d_ws (64 KB, L2-resident).
//   2. main: contiguous float4 copy-add; pe fetched per row (wave-uniform
//      broadcast load, L2-hit). No transcendentals in the hot loop.

typedef float f32x4 __attribute__((ext_vector_type(4)));

constexpr int B_ = 16, C_ = 64, H_ = 256, W_ = 256;
constexpr int N4      = B_ * C_ * H_ * W_ / 4;  // 16,777,216 float4s
constexpr int TABLE_N = C_ * H_;                // 16,384 entries

__global__ void __launch_bounds__(256) pe_table_kernel(float* __restrict__ pe) {
    const float LOG2_10000_OVER_C = 13.287712379549449f / 64.0f;  // log2(1e4)/C
    const int t = blockIdx.x * blockDim.x + threadIdx.x;          // c*256 + h
    if (t >= TABLE_N) return;
    const int h = t & (H_ - 1);
    const int c = t >> 8;
    const float freq = exp2f(-(float)(c & ~1) * LOG2_10000_OVER_C);
    const float arg  = (float)h * freq;
    pe[t] = (c & 1) ? cosf(arg) : sinf(arg);
}

__global__ void __launch_bounds__(256) PositionalEncoding_56805237457391_kernel(
    const f32x4* __restrict__ x, f32x4* __restrict__ out,
    const float* __restrict__ pe) {
    const int stride = gridDim.x * blockDim.x;  // 1,048,576
    // N4 / stride = 16 -> 8 iterations of 2 independent float4s each.
    for (int i = blockIdx.x * blockDim.x + threadIdx.x; i + stride < N4;
         i += 2 * stride) {
        const int j = i + stride;
        // row within (C,H): global row = i>>6 (64 float4s per W-row);
        // pe index = row mod (C*H).
        const float p0 = pe[(i >> 6) & (TABLE_N - 1)];
        const float p1 = pe[(j >> 6) & (TABLE_N - 1)];
        f32x4 v0 = x[i];
        f32x4 v1 = x[j];
        out[i] = v0 + p0;
        out[j] = v1 + p1;
    }
}

extern "C" void kernel_launch(void* const* d_in, const int* in_sizes, int n_in,
                              void* d_out, int out_size, void* d_ws, size_t ws_size,
                              hipStream_t stream) {
    const f32x4* x = (const f32x4*)d_in[0];
    f32x4* out = (f32x4*)d_out;
    float* pe = (float*)d_ws;

    pe_table_kernel<<<TABLE_N / 256, 256, 0, stream>>>(pe);

    const int block = 256;
    const int grid  = 4096;  // 16 blocks/CU; stride 1,048,576 = N4/16
    PositionalEncoding_56805237457391_kernel<<<grid, block, 0, stream>>>(x, out, pe);
}

// Round 4
// 106.636 us; speedup vs baseline: 1.1840x; 1.0969x over previous
//
#include <hip/hip_runtime.h>

// out[b,c,h,w] = x[b,c,h,w] + pe(c,h), x: (16,64,256,256) fp32 NCHW.
// One W-row (256 floats = 64 float4s) per wave-instruction: lane i reads
// float4 i of the row -> 1 KB fully-coalesced per instruction.
// Each wave processes 8 consecutive rows per iteration -> 8 independent
// loads in flight over a contiguous 8 KB window. pe is wave-uniform per row,
// computed inline (1 sincos per 1 KB moved - negligible, proven by R3).

typedef float f32x4 __attribute__((ext_vector_type(4)));

constexpr int B_ = 16, C_ = 64, H_ = 256, W_ = 256;
constexpr int ROWS    = B_ * C_ * H_;  // 262,144 rows of 64 float4s
constexpr int TABLE_N = C_ * H_;       // pe period in rows = 16,384
constexpr int ROWS_PER_BLOCK = 128;    // 2048 blocks cover all rows exactly

__global__ void __launch_bounds__(256) PositionalEncoding_56805237457391_kernel(
    const f32x4* __restrict__ x, f32x4* __restrict__ out) {
    const float LOG2_10000_OVER_C = 13.287712379549449f / 64.0f;  // log2(1e4)/C

    const int lane = threadIdx.x & 63;
    const int wave = threadIdx.x >> 6;  // 0..3

    int rowBase = blockIdx.x * ROWS_PER_BLOCK + wave * 8;
    for (int it = 0; it < ROWS_PER_BLOCK / 32; ++it, rowBase += 32) {
        f32x4 v[8];
        float p[8];
#pragma unroll
        for (int t = 0; t < 8; ++t) {
            const size_t idx = (size_t)(rowBase + t) * 64 + lane;
            v[t] = x[idx];
        }
#pragma unroll
        for (int t = 0; t < 8; ++t) {
            const int r = (rowBase + t) & (TABLE_N - 1);  // c*256 + h
            const int h = r & (H_ - 1);
            const int c = r >> 8;
            const float freq = exp2f(-(float)(c & ~1) * LOG2_10000_OVER_C);
            const float arg  = (float)h * freq;
            p[t] = (c & 1) ? cosf(arg) : sinf(arg);
        }
#pragma unroll
        for (int t = 0; t < 8; ++t) {
            const size_t idx = (size_t)(rowBase + t) * 64 + lane;
            out[idx] = v[t] + p[t];
        }
    }
}

extern "C" void kernel_launch(void* const* d_in, const int* in_sizes, int n_in,
                              void* d_out, int out_size, void* d_ws, size_t ws_size,
                              hipStream_t stream) {
    const f32x4* x = (const f32x4*)d_in[0];
    f32x4* out = (f32x4*)d_out;

    const int block = 256;
    const int grid  = ROWS / ROWS_PER_BLOCK;  // 2048 -> 8 blocks/CU, full occupancy
    PositionalEncoding_56805237457391_kernel<<<grid, block, 0, stream>>>(x, out);
}

// Round 5
// 83.158 us; speedup vs baseline: 1.5183x; 1.2823x over previous
//
#include <hip/hip_runtime.h>

// out[b,c,h,w] = x[b,c,h,w] + pe(c,h), x: (16,64,256,256) fp32 NCHW.
// R4 structure (proven tied-best): one W-row (64 float4s) per wave-instruction,
// 8 consecutive rows in flight per wave, contiguous 128-row block windows.
// R5 single change: nontemporal stores (bypass L2 write-allocate) to cut
// dirty-eviction contention with the read stream. Loads stay normal.

typedef float f32x4 __attribute__((ext_vector_type(4)));

constexpr int B_ = 16, C_ = 64, H_ = 256, W_ = 256;
constexpr int ROWS    = B_ * C_ * H_;  // 262,144 rows of 64 float4s
constexpr int TABLE_N = C_ * H_;       // pe period in rows = 16,384
constexpr int ROWS_PER_BLOCK = 128;    // 2048 blocks cover all rows exactly

__global__ void __launch_bounds__(256) PositionalEncoding_56805237457391_kernel(
    const f32x4* __restrict__ x, f32x4* __restrict__ out) {
    const float LOG2_10000_OVER_C = 13.287712379549449f / 64.0f;  // log2(1e4)/C

    const int lane = threadIdx.x & 63;
    const int wave = threadIdx.x >> 6;  // 0..3

    int rowBase = blockIdx.x * ROWS_PER_BLOCK + wave * 8;
    for (int it = 0; it < ROWS_PER_BLOCK / 32; ++it, rowBase += 32) {
        f32x4 v[8];
        float p[8];
#pragma unroll
        for (int t = 0; t < 8; ++t) {
            const size_t idx = (size_t)(rowBase + t) * 64 + lane;
            v[t] = x[idx];
        }
#pragma unroll
        for (int t = 0; t < 8; ++t) {
            const int r = (rowBase + t) & (TABLE_N - 1);  // c*256 + h
            const int h = r & (H_ - 1);
            const int c = r >> 8;
            const float freq = exp2f(-(float)(c & ~1) * LOG2_10000_OVER_C);
            const float arg  = (float)h * freq;
            p[t] = (c & 1) ? cosf(arg) : sinf(arg);
        }
#pragma unroll
        for (int t = 0; t < 8; ++t) {
            const size_t idx = (size_t)(rowBase + t) * 64 + lane;
            __builtin_nontemporal_store(v[t] + p[t], out + idx);
        }
    }
}

extern "C" void kernel_launch(void* const* d_in, const int* in_sizes, int n_in,
                              void* d_out, int out_size, void* d_ws, size_t ws_size,
                              hipStream_t stream) {
    const f32x4* x = (const f32x4*)d_in[0];
    f32x4* out = (f32x4*)d_out;

    const int block = 256;
    const int grid  = ROWS / ROWS_PER_BLOCK;  // 2048 -> 8 blocks/CU
    PositionalEncoding_56805237457391_kernel<<<grid, block, 0, stream>>>(x, out);
}